// Round 1
// baseline (2197.811 us; speedup 1.0000x reference)
//
#include <hip/hip_runtime.h>
#include <math.h>

#define N_NODES 100000
#define N_EDGES 1600000
#define DIM 64
#define N_LAYERS 6
#define N_COEF 8
#define KFEAT (DIM * 9)   // 576 features per node: per d -> silu + 8 spline bases

// ---------------------------------------------------------------------------
// Fold base_w, spline_w, spline_s into one combined weight matrix per layer:
// Wc[l][m][o], m = d*9 + r; r==0 -> base_w[l][o][d]; r==1+k -> sw[l][o][d][k]*ss[l][o][d]
// Stored [m][o] so the GEMM reads are lane-coalesced.
// ---------------------------------------------------------------------------
__global__ void build_wc_kernel(const float* __restrict__ bw,
                                const float* __restrict__ sw,
                                const float* __restrict__ ss,
                                float* __restrict__ wc) {
    int idx = blockIdx.x * blockDim.x + threadIdx.x;
    if (idx >= N_LAYERS * KFEAT * DIM) return;
    int o = idx & 63;
    int m = (idx >> 6) % KFEAT;
    int l = idx / (KFEAT * DIM);
    int d = m / 9;
    int r = m % 9;
    float v;
    if (r == 0) {
        v = bw[(l * DIM + o) * DIM + d];
    } else {
        int k = r - 1;
        v = sw[((l * DIM + o) * DIM + d) * N_COEF + k] * ss[(l * DIM + o) * DIM + d];
    }
    wc[(l * KFEAT + m) * DIM + o] = v;
}

// ---------------------------------------------------------------------------
// SpMM: y[i,:] = sum_{e : row[e]==i} val[e] * x[col[e], :]
// edge_row is sorted -> binary search the segment. One 64-lane wave per node,
// lane = feature index d.
// ---------------------------------------------------------------------------
__global__ __launch_bounds__(256) void spmm_kernel(const int* __restrict__ erow,
                                                   const int* __restrict__ ecol,
                                                   const float* __restrict__ eval_,
                                                   const float* __restrict__ x,
                                                   float* __restrict__ y) {
    int wid = (blockIdx.x * blockDim.x + threadIdx.x) >> 6;  // node id
    int lane = threadIdx.x & 63;
    if (wid >= N_NODES) return;

    // lower_bound(erow, wid)
    int a = 0, b = N_EDGES;
    while (a < b) { int m = (a + b) >> 1; if (erow[m] < wid) a = m + 1; else b = m; }
    int start = a;
    // lower_bound(erow, wid+1), starting from `start`
    b = N_EDGES;
    while (a < b) { int m = (a + b) >> 1; if (erow[m] < wid + 1) a = m + 1; else b = m; }
    int end = a;

    float acc = 0.f;
    for (int e = start; e < end; ++e) {
        float v = eval_[e];
        int c = ecol[e];
        acc += v * x[c * DIM + lane];
    }
    y[wid * DIM + lane] = acc;
}

// ---------------------------------------------------------------------------
// Cubic B-spline bases on the uniform extended grid g[i] = (i-3)*0.4 - 1,
// i = 0..11 (GRID_SIZE=5, SPLINE_ORDER=3). Returns 8 bases in bb[0..7].
// ---------------------------------------------------------------------------
__device__ __forceinline__ void bspline8(float xv, float* bb) {
    const float h = 0.4f;
    float b[11];
#pragma unroll
    for (int j = 0; j < 11; ++j) {
        float gj  = (float)(j - 3) * h - 1.f;
        float gj1 = (float)(j - 2) * h - 1.f;
        b[j] = (xv >= gj && xv < gj1) ? 1.f : 0.f;
    }
#pragma unroll
    for (int p = 1; p <= 3; ++p) {
        float inv = 1.f / ((float)p * h);
#pragma unroll
        for (int j = 0; j + p < 11; ++j) {
            float gj   = (float)(j - 3) * h - 1.f;
            float gjp1 = (float)(j - 3 + p + 1) * h - 1.f;
            b[j] = (xv - gj) * inv * b[j] + (gjp1 - xv) * inv * b[j + 1];
        }
    }
#pragma unroll
    for (int k = 0; k < 8; ++k) bb[k] = b[k];
}

// ---------------------------------------------------------------------------
// Fused KANLinear: feat = [silu(x_d), B_0(x_d)..B_7(x_d)] (K=576), then
// out[n,o] = sum_m feat[n,m] * wc[m,o].  Block = 256 threads = 4 waves,
// TILE = 16 nodes staged in LDS; each thread owns one output column o for
// 4 nodes; wc element loaded once per wave-iteration and reused 4x.
// ---------------------------------------------------------------------------
__global__ __launch_bounds__(256) void kan_kernel(const float* __restrict__ xin,
                                                  const float* __restrict__ wc,
                                                  float* __restrict__ out) {
    __shared__ float feat[16][KFEAT];  // 36.9 KB
    int tid = threadIdx.x;
    int lane = tid & 63;
    int wv = tid >> 6;  // 0..3
    int node0 = blockIdx.x * 16;

    // ---- feature phase: wave wv computes nodes {wv, wv+4, wv+8, wv+12}, lane = d
#pragma unroll
    for (int j = 0; j < 4; ++j) {
        int nl = wv + 4 * j;
        int n = node0 + nl;
        float xv = xin[n * DIM + lane];
        float s = xv / (1.f + expf(-xv));  // silu
        feat[nl][lane * 9 + 0] = s;
        float bb[8];
        bspline8(xv, bb);
#pragma unroll
        for (int k = 0; k < 8; ++k) feat[nl][lane * 9 + 1 + k] = bb[k];
    }
    __syncthreads();

    // ---- GEMM phase: thread owns column o = lane for nodes {wv, wv+4, wv+8, wv+12}
    float acc[4] = {0.f, 0.f, 0.f, 0.f};
    for (int m = 0; m < KFEAT; ++m) {
        float w = wc[m * DIM + lane];
#pragma unroll
        for (int j = 0; j < 4; ++j) acc[j] += feat[wv + 4 * j][m] * w;
    }
#pragma unroll
    for (int j = 0; j < 4; ++j) {
        int n = node0 + wv + 4 * j;
        out[n * DIM + lane] = acc[j];
    }
}

extern "C" void kernel_launch(void* const* d_in, const int* in_sizes, int n_in,
                              void* d_out, int out_size, void* d_ws, size_t ws_size,
                              hipStream_t stream) {
    const float* x     = (const float*)d_in[0];
    const float* eval_ = (const float*)d_in[1];
    const float* bw    = (const float*)d_in[2];
    const float* sw    = (const float*)d_in[3];
    const float* ss    = (const float*)d_in[4];
    const int*   erow  = (const int*)d_in[5];
    const int*   ecol  = (const int*)d_in[6];
    float* out = (float*)d_out;

    // ws layout: [A: 100000*64 f32 = 25.6MB][Wc: 6*576*64 f32 = 884KB]
    float* A  = (float*)d_ws;
    float* wc = (float*)((char*)d_ws + (size_t)N_NODES * DIM * sizeof(float));

    build_wc_kernel<<<(N_LAYERS * KFEAT * DIM + 255) / 256, 256, 0, stream>>>(bw, sw, ss, wc);

    const int SPMM_BLOCKS = N_NODES / 4;   // 4 waves per 256-thread block
    const int KAN_BLOCKS  = N_NODES / 16;  // 16 nodes per block

    // chain: x -spmm-> out -k0-> A -k1-> out -spmm-> A -k2-> out -k3-> A -spmm-> out -k4-> A -k5-> out
    spmm_kernel<<<SPMM_BLOCKS, 256, 0, stream>>>(erow, ecol, eval_, x, out);
    kan_kernel<<<KAN_BLOCKS, 256, 0, stream>>>(out, wc + 0 * KFEAT * DIM, A);
    kan_kernel<<<KAN_BLOCKS, 256, 0, stream>>>(A,   wc + 1 * KFEAT * DIM, out);

    spmm_kernel<<<SPMM_BLOCKS, 256, 0, stream>>>(erow, ecol, eval_, out, A);
    kan_kernel<<<KAN_BLOCKS, 256, 0, stream>>>(A,   wc + 2 * KFEAT * DIM, out);
    kan_kernel<<<KAN_BLOCKS, 256, 0, stream>>>(out, wc + 3 * KFEAT * DIM, A);

    spmm_kernel<<<SPMM_BLOCKS, 256, 0, stream>>>(erow, ecol, eval_, A, out);
    kan_kernel<<<KAN_BLOCKS, 256, 0, stream>>>(out, wc + 4 * KFEAT * DIM, A);
    kan_kernel<<<KAN_BLOCKS, 256, 0, stream>>>(A,   wc + 5 * KFEAT * DIM, out);
}

// Round 2
// 576.161 us; speedup vs baseline: 3.8146x; 3.8146x over previous
//
#include <hip/hip_runtime.h>
#include <math.h>

#define N_NODES 100000
#define N_EDGES 1600000
#define DIM 64
#define N_LAYERS 6
#define N_COEF 8
#define NSTEP 18              // K=576 / 32
#define NTILE 32              // nodes per kan block-tile
#define KAN_TILES (N_NODES / NTILE)  // 3125

typedef _Float16 f16x8 __attribute__((ext_vector_type(8)));
typedef float f32x4 __attribute__((ext_vector_type(4)));

// ---------------------------------------------------------------------------
// Weights in MFMA B-fragment-linear layout, f16 hi/lo split.
// K ordering (r-major): k = r*64 + d; r==0 -> silu branch (base_w), r=1..8 ->
// spline basis r-1. Fragment for (layer l, product p, kstep s, o-tile nt):
// 64 lanes x 16B; lane holds B[k = s*32+(lane>>4)*8+j][o = nt*16+(lane&15)].
// ---------------------------------------------------------------------------
__global__ void build_wcf(const float* __restrict__ bw,
                          const float* __restrict__ sw,
                          const float* __restrict__ ss,
                          uint4* __restrict__ wcf) {
    int idx = blockIdx.x * blockDim.x + threadIdx.x;
    if (idx >= N_LAYERS * NSTEP * 4 * 64) return;
    int lane = idx & 63;
    int nt   = (idx >> 6) & 3;
    int s    = (idx >> 8) % NSTEP;
    int l    = idx / (64 * 4 * NSTEP);
    int o = nt * 16 + (lane & 15);

    unsigned short hi[8], lo[8];
#pragma unroll
    for (int j = 0; j < 8; ++j) {
        int k = s * 32 + ((lane >> 4) << 3) + j;
        int r = k >> 6, d = k & 63;
        float v;
        if (r == 0) v = bw[(l * DIM + o) * DIM + d];
        else        v = sw[((l * DIM + o) * DIM + d) * N_COEF + (r - 1)] *
                        ss[(l * DIM + o) * DIM + d];
        _Float16 h = (_Float16)v;
        float lv = v - (float)h;
        _Float16 lo16 = (_Float16)lv;
        hi[j] = __builtin_bit_cast(unsigned short, h);
        lo[j] = __builtin_bit_cast(unsigned short, lo16);
    }
    uint4 uh, ul;
    uh.x = (unsigned)hi[0] | ((unsigned)hi[1] << 16);
    uh.y = (unsigned)hi[2] | ((unsigned)hi[3] << 16);
    uh.z = (unsigned)hi[4] | ((unsigned)hi[5] << 16);
    uh.w = (unsigned)hi[6] | ((unsigned)hi[7] << 16);
    ul.x = (unsigned)lo[0] | ((unsigned)lo[1] << 16);
    ul.y = (unsigned)lo[2] | ((unsigned)lo[3] << 16);
    ul.z = (unsigned)lo[4] | ((unsigned)lo[5] << 16);
    ul.w = (unsigned)lo[6] | ((unsigned)lo[7] << 16);
    wcf[(((l * 2 + 0) * NSTEP + s) * 4 + nt) * 64 + lane] = uh;
    wcf[(((l * 2 + 1) * NSTEP + s) * 4 + nt) * 64 + lane] = ul;
}

// ---------------------------------------------------------------------------
// row_ptr build: one binary search per node, once per call (reused 3x).
// ---------------------------------------------------------------------------
__global__ void build_rowptr(const int* __restrict__ erow, int* __restrict__ rp) {
    int i = blockIdx.x * blockDim.x + threadIdx.x;
    if (i > N_NODES) return;
    if (i == N_NODES) { rp[i] = N_EDGES; return; }
    int a = 0, b = N_EDGES;
    while (a < b) { int m = (a + b) >> 1; if (erow[m] < i) a = m + 1; else b = m; }
    rp[i] = a;
}

// ---------------------------------------------------------------------------
// SpMM with row_ptr + 4-deep gather ILP. One 64-lane wave per node (lane = d).
// ---------------------------------------------------------------------------
__global__ __launch_bounds__(256) void spmm_kernel(const int* __restrict__ rp,
                                                   const int* __restrict__ ecol,
                                                   const float* __restrict__ ev,
                                                   const float* __restrict__ x,
                                                   float* __restrict__ y) {
    int wid = (blockIdx.x * blockDim.x + threadIdx.x) >> 6;
    int lane = threadIdx.x & 63;
    if (wid >= N_NODES) return;
    int e = rp[wid], end = rp[wid + 1];
    float acc = 0.f;
    for (; e + 4 <= end; e += 4) {
        int c0 = ecol[e + 0], c1 = ecol[e + 1], c2 = ecol[e + 2], c3 = ecol[e + 3];
        float v0 = ev[e + 0], v1 = ev[e + 1], v2 = ev[e + 2], v3 = ev[e + 3];
        float x0 = x[(size_t)c0 * DIM + lane];
        float x1 = x[(size_t)c1 * DIM + lane];
        float x2 = x[(size_t)c2 * DIM + lane];
        float x3 = x[(size_t)c3 * DIM + lane];
        acc += v0 * x0; acc += v1 * x1; acc += v2 * x2; acc += v3 * x3;
    }
    for (; e < end; ++e) acc += ev[e] * x[(size_t)ecol[e] * DIM + lane];
    y[(size_t)wid * DIM + lane] = acc;
}

// ---------------------------------------------------------------------------
// Fused KANLinear via f16 MFMA (16x16x32), weights hi/lo (2 products).
// Block = 256 thr (4 waves); wave w owns o-tile w (16 outputs), holds its
// full-K B-fragments in registers (36 x f16x8 = 144 VGPR). Loop over 32-node
// tiles: all threads compute features (closed-form cubic B-spline) into LDS
// (A-fragment-linear layout, conflict-free ds_read_b128), then each wave does
// 18 ksteps x 2 mtiles x 2 products MFMAs.
// ---------------------------------------------------------------------------
__global__ __launch_bounds__(256, 2) void kan_mfma(const float* __restrict__ xin,
                                                   const uint4* __restrict__ wl,
                                                   float* __restrict__ out) {
    __shared__ alignas(16) char lds[2 * NSTEP * 64 * 16];  // 36864 B

    int tid = threadIdx.x;
    int lane = tid & 63;
    int w = tid >> 6;

    // --- load B fragments (hi/lo) for this wave's o-tile, full K ---
    f16x8 bhi[NSTEP], blo[NSTEP];
#pragma unroll
    for (int s = 0; s < NSTEP; ++s) {
        uint4 uh = wl[((0 * NSTEP + s) * 4 + w) * 64 + lane];
        uint4 ul = wl[((1 * NSTEP + s) * 4 + w) * 64 + lane];
        bhi[s] = __builtin_bit_cast(f16x8, uh);
        blo[s] = __builtin_bit_cast(f16x8, ul);
    }

    // feature-phase thread mapping: node n = tid>>3 (0..31), d-pair id dp = tid&7
    int fn = tid >> 3;
    int fdp = tid & 7;
    int fmt = fn >> 4, frow = fn & 15;

    for (int tile = blockIdx.x; tile < KAN_TILES; tile += gridDim.x) {
        int node0 = tile * NTILE;
        __syncthreads();  // previous iteration's LDS reads complete

        // ---- feature phase: 8 elements per thread as 4 d-pairs ----
#pragma unroll
        for (int i = 0; i < 4; ++i) {
            int d = fdp * 2 + i * 16;  // even
            const float* xp = &xin[(size_t)(node0 + fn) * DIM + d];
            float xa = xp[0], xb = xp[1];

            float fa[9], fb[9];
#pragma unroll
            for (int e = 0; e < 2; ++e) {
                float xv = e ? xb : xa;
                float* f = e ? fb : fa;
                // silu
                f[0] = xv / (1.f + __expf(-xv));
                // cell + local coord on extended grid [-2.2, 2.2), h = 0.4
                float t = xv * 2.5f + 5.5f;
                float fl = floorf(t);
                float u = t - fl;
                int c = (int)fl;
                bool valid = (t >= 0.f) && (t < 11.f);
                c = c < -4 ? -4 : (c > 14 ? 14 : c);
                float u2 = u * u, u3 = u2 * u, um = 1.f - u;
                const float k6 = 1.f / 6.f;
                float N0 = um * um * um * k6;
                float N1 = (3.f * u3 - 6.f * u2 + 4.f) * k6;
                float N2 = (-3.f * u3 + 3.f * u2 + 3.f * u + 1.f) * k6;
                float N3 = u3 * k6;
                if (!valid) { N0 = 0.f; N1 = 0.f; N2 = 0.f; N3 = 0.f; }
                int qb = c - 3;  // basis index of N0
#pragma unroll
                for (int k = 0; k < 8; ++k) {
                    int q = k - qb;
                    f[k + 1] = (q == 0) ? N0 : (q == 1) ? N1 : (q == 2) ? N2 : (q == 3) ? N3 : 0.f;
                }
            }
            // write 9 f16-pairs: m = r*64 + d -> s = 2r + (d>>5), kg = (d>>3)&3, j = d&7
            int kg = (d >> 3) & 3, j = d & 7;
#pragma unroll
            for (int r = 0; r < 9; ++r) {
                int s = r * 2 + (d >> 5);
                _Float16 ha = (_Float16)fa[r];
                _Float16 hb = (_Float16)fb[r];
                unsigned pu = (unsigned)__builtin_bit_cast(unsigned short, ha) |
                              ((unsigned)__builtin_bit_cast(unsigned short, hb) << 16);
                int addr = ((fmt * NSTEP + s) * 64 + kg * 16 + frow) * 16 + j * 2;
                *(unsigned*)(&lds[addr]) = pu;
            }
        }
        __syncthreads();

        // ---- MFMA phase ----
        f32x4 acc0 = {0.f, 0.f, 0.f, 0.f};
        f32x4 acc1 = {0.f, 0.f, 0.f, 0.f};
#pragma unroll
        for (int s = 0; s < NSTEP; ++s) {
            f16x8 a0 = *(const f16x8*)(&lds[((0 * NSTEP + s) * 64 + lane) * 16]);
            f16x8 a1 = *(const f16x8*)(&lds[((1 * NSTEP + s) * 64 + lane) * 16]);
            acc0 = __builtin_amdgcn_mfma_f32_16x16x32_f16(a0, bhi[s], acc0, 0, 0, 0);
            acc0 = __builtin_amdgcn_mfma_f32_16x16x32_f16(a0, blo[s], acc0, 0, 0, 0);
            acc1 = __builtin_amdgcn_mfma_f32_16x16x32_f16(a1, bhi[s], acc1, 0, 0, 0);
            acc1 = __builtin_amdgcn_mfma_f32_16x16x32_f16(a1, blo[s], acc1, 0, 0, 0);
        }

        // ---- store: C layout col=lane&15, row=(lane>>4)*4+r ----
        int o = w * 16 + (lane & 15);
        int rbase = (lane >> 4) * 4;
#pragma unroll
        for (int r = 0; r < 4; ++r) {
            out[(size_t)(node0 + rbase + r) * DIM + o]      = acc0[r];
            out[(size_t)(node0 + 16 + rbase + r) * DIM + o] = acc1[r];
        }
    }
}

extern "C" void kernel_launch(void* const* d_in, const int* in_sizes, int n_in,
                              void* d_out, int out_size, void* d_ws, size_t ws_size,
                              hipStream_t stream) {
    const float* x     = (const float*)d_in[0];
    const float* eval_ = (const float*)d_in[1];
    const float* bw    = (const float*)d_in[2];
    const float* sw    = (const float*)d_in[3];
    const float* ss    = (const float*)d_in[4];
    const int*   erow  = (const int*)d_in[5];
    const int*   ecol  = (const int*)d_in[6];
    float* out = (float*)d_out;

    // ws layout: [A: 25.6MB][wcf: 884736B][row_ptr: 400004B]
    float* A   = (float*)d_ws;
    uint4* wcf = (uint4*)((char*)d_ws + (size_t)N_NODES * DIM * sizeof(float));
    int*   rp  = (int*)((char*)d_ws + (size_t)N_NODES * DIM * sizeof(float) + 884736);

    const size_t WL = (size_t)2 * NSTEP * 4 * 64;  // uint4 per layer

    build_wcf<<<(N_LAYERS * NSTEP * 4 * 64 + 255) / 256, 256, 0, stream>>>(bw, sw, ss, wcf);
    build_rowptr<<<(N_NODES + 256) / 256, 256, 0, stream>>>(erow, rp);

    const int SPMM_BLOCKS = N_NODES / 4;
    const int KAN_BLOCKS = 512;

    spmm_kernel<<<SPMM_BLOCKS, 256, 0, stream>>>(rp, ecol, eval_, x, out);
    kan_mfma<<<KAN_BLOCKS, 256, 0, stream>>>(out, wcf + 0 * WL, A);
    kan_mfma<<<KAN_BLOCKS, 256, 0, stream>>>(A,   wcf + 1 * WL, out);

    spmm_kernel<<<SPMM_BLOCKS, 256, 0, stream>>>(rp, ecol, eval_, out, A);
    kan_mfma<<<KAN_BLOCKS, 256, 0, stream>>>(A,   wcf + 2 * WL, out);
    kan_mfma<<<KAN_BLOCKS, 256, 0, stream>>>(out, wcf + 3 * WL, A);

    spmm_kernel<<<SPMM_BLOCKS, 256, 0, stream>>>(rp, ecol, eval_, A, out);
    kan_mfma<<<KAN_BLOCKS, 256, 0, stream>>>(out, wcf + 4 * WL, A);
    kan_mfma<<<KAN_BLOCKS, 256, 0, stream>>>(A,   wcf + 5 * WL, out);
}

// Round 3
// 388.098 us; speedup vs baseline: 5.6630x; 1.4846x over previous
//
#include <hip/hip_runtime.h>
#include <math.h>

#define N_NODES 100000
#define N_EDGES 1600000
#define DIM 64
#define N_LAYERS 6
#define N_COEF 8
#define NSTEP 18              // K=576 / 32
#define NTILE 32              // nodes per kan block-tile
#define KAN_TILES (N_NODES / NTILE)  // 3125

typedef _Float16 f16x8 __attribute__((ext_vector_type(8)));
typedef float f32x4 __attribute__((ext_vector_type(4)));

__device__ __forceinline__ unsigned f16u(float v) {
    return (unsigned)__builtin_bit_cast(unsigned short, (_Float16)v);
}

// ---------------------------------------------------------------------------
// Weights in MFMA B-fragment-linear layout, f16 hi/lo split.
// K ordering (d-major): k = d*9 + r; r==0 -> silu branch (base_w), r=1..8 ->
// spline basis r-1. Fragment for (layer l, product p, kstep s, o-tile nt):
// lane holds B[k = s*32+(lane>>4)*8+j][o = nt*16+(lane&15)], j=0..7.
// ---------------------------------------------------------------------------
__global__ void build_wcf(const float* __restrict__ bw,
                          const float* __restrict__ sw,
                          const float* __restrict__ ss,
                          uint4* __restrict__ wcf) {
    int idx = blockIdx.x * blockDim.x + threadIdx.x;
    if (idx >= N_LAYERS * NSTEP * 4 * 64) return;
    int lane = idx & 63;
    int nt   = (idx >> 6) & 3;
    int s    = (idx >> 8) % NSTEP;
    int l    = idx / (64 * 4 * NSTEP);
    int o = nt * 16 + (lane & 15);

    unsigned short hi[8], lo[8];
#pragma unroll
    for (int j = 0; j < 8; ++j) {
        int k = s * 32 + ((lane >> 4) << 3) + j;
        int d = k / 9;
        int r = k - d * 9;
        float v;
        if (r == 0) v = bw[(l * DIM + o) * DIM + d];
        else        v = sw[((l * DIM + o) * DIM + d) * N_COEF + (r - 1)] *
                        ss[(l * DIM + o) * DIM + d];
        _Float16 h = (_Float16)v;
        float lv = v - (float)h;
        _Float16 lo16 = (_Float16)lv;
        hi[j] = __builtin_bit_cast(unsigned short, h);
        lo[j] = __builtin_bit_cast(unsigned short, lo16);
    }
    uint4 uh, ul;
    uh.x = (unsigned)hi[0] | ((unsigned)hi[1] << 16);
    uh.y = (unsigned)hi[2] | ((unsigned)hi[3] << 16);
    uh.z = (unsigned)hi[4] | ((unsigned)hi[5] << 16);
    uh.w = (unsigned)hi[6] | ((unsigned)hi[7] << 16);
    ul.x = (unsigned)lo[0] | ((unsigned)lo[1] << 16);
    ul.y = (unsigned)lo[2] | ((unsigned)lo[3] << 16);
    ul.z = (unsigned)lo[4] | ((unsigned)lo[5] << 16);
    ul.w = (unsigned)lo[6] | ((unsigned)lo[7] << 16);
    wcf[(((l * 2 + 0) * NSTEP + s) * 4 + nt) * 64 + lane] = uh;
    wcf[(((l * 2 + 1) * NSTEP + s) * 4 + nt) * 64 + lane] = ul;
}

// ---------------------------------------------------------------------------
// row_ptr build: one binary search per node, once per call (reused 3x).
// ---------------------------------------------------------------------------
__global__ void build_rowptr(const int* __restrict__ erow, int* __restrict__ rp) {
    int i = blockIdx.x * blockDim.x + threadIdx.x;
    if (i > N_NODES) return;
    if (i == N_NODES) { rp[i] = N_EDGES; return; }
    int a = 0, b = N_EDGES;
    while (a < b) { int m = (a + b) >> 1; if (erow[m] < i) a = m + 1; else b = m; }
    rp[i] = a;
}

// ---------------------------------------------------------------------------
// SpMM with row_ptr + 4-deep gather ILP. One 64-lane wave per node (lane = d).
// ---------------------------------------------------------------------------
__global__ __launch_bounds__(256) void spmm_kernel(const int* __restrict__ rp,
                                                   const int* __restrict__ ecol,
                                                   const float* __restrict__ ev,
                                                   const float* __restrict__ x,
                                                   float* __restrict__ y) {
    int wid = (blockIdx.x * blockDim.x + threadIdx.x) >> 6;
    int lane = threadIdx.x & 63;
    if (wid >= N_NODES) return;
    int e = rp[wid], end = rp[wid + 1];
    float acc = 0.f;
    for (; e + 4 <= end; e += 4) {
        int c0 = ecol[e + 0], c1 = ecol[e + 1], c2 = ecol[e + 2], c3 = ecol[e + 3];
        float v0 = ev[e + 0], v1 = ev[e + 1], v2 = ev[e + 2], v3 = ev[e + 3];
        float x0 = x[(size_t)c0 * DIM + lane];
        float x1 = x[(size_t)c1 * DIM + lane];
        float x2 = x[(size_t)c2 * DIM + lane];
        float x3 = x[(size_t)c3 * DIM + lane];
        acc += v0 * x0; acc += v1 * x1; acc += v2 * x2; acc += v3 * x3;
    }
    for (; e < end; ++e) acc += ev[e] * x[(size_t)ecol[e] * DIM + lane];
    y[(size_t)wid * DIM + lane] = acc;
}

// ---------------------------------------------------------------------------
// Spline window: 4 nonzero cubic B-spline bases as f16 pairs, positioned into
// an 8-slot (128-bit) window via 64-bit shifts. Slots kb=0..3 -> lo, 4..7 -> hi.
// ---------------------------------------------------------------------------
__device__ __forceinline__ void spline_window(float xv, unsigned long long& lo,
                                              unsigned long long& hi) {
    float t = xv * 2.5f + 5.5f;        // grid units on extended grid, h=0.4
    float fl = floorf(t);
    float u = t - fl;
    int c = (int)fl;
    bool valid = (t >= 0.f) && (t < 11.f);
    float u2 = u * u, u3 = u2 * u, um = 1.f - u;
    const float k6 = 1.f / 6.f;
    float N0 = um * um * um * k6;
    float N1 = (3.f * u3 - 6.f * u2 + 4.f) * k6;
    float N2 = (-3.f * u3 + 3.f * u2 + 3.f * u + 1.f) * k6;
    float N3 = u3 * k6;
    if (!valid) { N0 = 0.f; N1 = 0.f; N2 = 0.f; N3 = 0.f; }
    unsigned n01 = f16u(N0) | (f16u(N1) << 16);
    unsigned n23 = f16u(N2) | (f16u(N3) << 16);
    unsigned long long big = (unsigned long long)n01 | ((unsigned long long)n23 << 32);
    int qb = c - 3;
    qb = qb < -3 ? -3 : (qb > 7 ? 7 : qb);   // invalid => big==0, clamp keeps shifts legal
    int sh = qb * 16;
    lo = 0; hi = 0;
    if (sh >= 0) {
        if (sh < 64) { lo = big << sh; hi = (big >> 1) >> (63 - sh); }  // N3>=0 => bit63==0
        else         { hi = big << (sh - 64); }
    } else {
        lo = big >> (-sh);
    }
}

// ---------------------------------------------------------------------------
// Fused KANLinear via f16 MFMA (16x16x32), weights hi/lo (2 products).
// LDS: XOR-swizzled row-major [32 nodes][576 f16] (1152 B rows). 16B block at
// logical octave koct of node n lives at physical octave koct ^ (n&7).
// Feature phase: thread owns 8 d's as 4 (even,odd) pairs -> 18 contiguous k
// slots -> 9 aligned ds_write_b32. MFMA phase: wave w = o-tile, 18 ksteps x
// 2 mtiles x 2 products, A-frags via conflict-free swizzled ds_read_b128.
// ---------------------------------------------------------------------------
__global__ __launch_bounds__(256, 4) void kan_mfma(const float* __restrict__ xin,
                                                   const uint4* __restrict__ wl,
                                                   float* __restrict__ out) {
    __shared__ alignas(16) char lds[NTILE * 1152];  // 36864 B

    int tid = threadIdx.x;
    int lane = tid & 63;
    int w = tid >> 6;
    int node0 = blockIdx.x * NTILE;

    // ---- feature phase: fn = node local, fq = quad of d ----
    int fn = tid >> 3;
    int fq = tid & 7;
    int Xsw = (fn & 7) << 4;
    int lbase = fn * 1152;
    const float* xrow = &xin[(size_t)(node0 + fn) * DIM];

#pragma unroll
    for (int i = 0; i < 2; ++i) {
        float4 xv4 = *(const float4*)(xrow + fq * 4 + i * 32);
#pragma unroll
        for (int p = 0; p < 2; ++p) {
            int d = fq * 4 + i * 32 + p * 2;   // even
            float xe = p ? xv4.z : xv4.x;
            float xo = p ? xv4.w : xv4.y;

            float se_f = xe * __builtin_amdgcn_rcpf(1.f + __expf(-xe));
            float so_f = xo * __builtin_amdgcn_rcpf(1.f + __expf(-xo));
            unsigned se = f16u(se_f), so = f16u(so_f);

            unsigned long long loE, hiE, loO, hiO;
            spline_window(xe, loE, hiE);
            spline_window(xo, loO, hiO);

            unsigned wv[9];
            wv[0] = se | ((unsigned)loE << 16);
            wv[1] = (unsigned)(loE >> 16);
            wv[2] = (unsigned)(loE >> 48) | ((unsigned)hiE << 16);
            wv[3] = (unsigned)(hiE >> 16);
            wv[4] = (unsigned)(hiE >> 48) | (so << 16);
            wv[5] = (unsigned)loO;
            wv[6] = (unsigned)(loO >> 32);
            wv[7] = (unsigned)hiO;
            wv[8] = (unsigned)(hiO >> 32);

            int base = lbase + 18 * d;   // d even -> 4B aligned
#pragma unroll
            for (int j = 0; j < 9; ++j)
                *(unsigned*)(&lds[(base + 4 * j) ^ Xsw]) = wv[j];
        }
    }
    __syncthreads();

    // ---- MFMA phase ----
    int row = lane & 15, kg = lane >> 4;
    int xr = (row & 7) << 4;
    int rb0 = row * 1152;
    int rb1 = (16 + row) * 1152;

    f32x4 acc0 = {0.f, 0.f, 0.f, 0.f};
    f32x4 acc1 = {0.f, 0.f, 0.f, 0.f};
#pragma unroll
    for (int s = 0; s < NSTEP; ++s) {
        uint4 uh = wl[((0 * NSTEP + s) * 4 + w) * 64 + lane];
        uint4 ul = wl[((1 * NSTEP + s) * 4 + w) * 64 + lane];
        f16x8 bhi = __builtin_bit_cast(f16x8, uh);
        f16x8 blo = __builtin_bit_cast(f16x8, ul);
        int pofs = ((s * 4 + kg) << 4) ^ xr;
        f16x8 a0 = *(const f16x8*)(&lds[rb0 + pofs]);
        f16x8 a1 = *(const f16x8*)(&lds[rb1 + pofs]);
        acc0 = __builtin_amdgcn_mfma_f32_16x16x32_f16(a0, bhi, acc0, 0, 0, 0);
        acc0 = __builtin_amdgcn_mfma_f32_16x16x32_f16(a0, blo, acc0, 0, 0, 0);
        acc1 = __builtin_amdgcn_mfma_f32_16x16x32_f16(a1, bhi, acc1, 0, 0, 0);
        acc1 = __builtin_amdgcn_mfma_f32_16x16x32_f16(a1, blo, acc1, 0, 0, 0);
    }

    // ---- store: C layout col=lane&15, row=(lane>>4)*4+r ----
    int o = w * 16 + (lane & 15);
    int rbase = (lane >> 4) * 4;
#pragma unroll
    for (int r = 0; r < 4; ++r) {
        out[(size_t)(node0 + rbase + r) * DIM + o]      = acc0[r];
        out[(size_t)(node0 + 16 + rbase + r) * DIM + o] = acc1[r];
    }
}

extern "C" void kernel_launch(void* const* d_in, const int* in_sizes, int n_in,
                              void* d_out, int out_size, void* d_ws, size_t ws_size,
                              hipStream_t stream) {
    const float* x     = (const float*)d_in[0];
    const float* eval_ = (const float*)d_in[1];
    const float* bw    = (const float*)d_in[2];
    const float* sw    = (const float*)d_in[3];
    const float* ss    = (const float*)d_in[4];
    const int*   erow  = (const int*)d_in[5];
    const int*   ecol  = (const int*)d_in[6];
    float* out = (float*)d_out;

    // ws layout: [A: 25.6MB][wcf: 884736B][row_ptr: 400004B]
    float* A   = (float*)d_ws;
    uint4* wcf = (uint4*)((char*)d_ws + (size_t)N_NODES * DIM * sizeof(float));
    int*   rp  = (int*)((char*)d_ws + (size_t)N_NODES * DIM * sizeof(float) + 884736);

    const size_t WL = (size_t)2 * NSTEP * 4 * 64;  // uint4 per layer

    build_wcf<<<(N_LAYERS * NSTEP * 4 * 64 + 255) / 256, 256, 0, stream>>>(bw, sw, ss, wcf);
    build_rowptr<<<(N_NODES + 256) / 256, 256, 0, stream>>>(erow, rp);

    const int SPMM_BLOCKS = N_NODES / 4;

    spmm_kernel<<<SPMM_BLOCKS, 256, 0, stream>>>(rp, ecol, eval_, x, out);
    kan_mfma<<<KAN_TILES, 256, 0, stream>>>(out, wcf + 0 * WL, A);
    kan_mfma<<<KAN_TILES, 256, 0, stream>>>(A,   wcf + 1 * WL, out);

    spmm_kernel<<<SPMM_BLOCKS, 256, 0, stream>>>(rp, ecol, eval_, out, A);
    kan_mfma<<<KAN_TILES, 256, 0, stream>>>(A,   wcf + 2 * WL, out);
    kan_mfma<<<KAN_TILES, 256, 0, stream>>>(out, wcf + 3 * WL, A);

    spmm_kernel<<<SPMM_BLOCKS, 256, 0, stream>>>(rp, ecol, eval_, A, out);
    kan_mfma<<<KAN_TILES, 256, 0, stream>>>(out, wcf + 4 * WL, A);
    kan_mfma<<<KAN_TILES, 256, 0, stream>>>(A,   wcf + 5 * WL, out);
}

// Round 4
// 358.674 us; speedup vs baseline: 6.1276x; 1.0820x over previous
//
#include <hip/hip_runtime.h>
#include <math.h>

#define N_NODES 100000
#define N_EDGES 1600000
#define DIM 64
#define N_LAYERS 6
#define N_COEF 8
#define NSTEP 18              // K=576 / 32
#define NTILE 32              // nodes per kan block-tile
#define KAN_TILES (N_NODES / NTILE)  // 3125
#define KAN_GRID 512

typedef _Float16 f16x8 __attribute__((ext_vector_type(8)));
typedef float f32x4 __attribute__((ext_vector_type(4)));

__device__ __forceinline__ unsigned f16u(float v) {
    return (unsigned)__builtin_bit_cast(unsigned short, (_Float16)v);
}

// ---------------------------------------------------------------------------
// Weights in MFMA B-fragment-linear layout, f16 hi/lo split.
// K ordering (d-major): k = d*9 + r; r==0 -> silu branch (base_w), r=1..8 ->
// spline basis r-1. Fragment for (layer l, product p, kstep s, o-tile nt):
// lane holds B[k = s*32+(lane>>4)*8+j][o = nt*16+(lane&15)], j=0..7.
// ---------------------------------------------------------------------------
__global__ void build_wcf(const float* __restrict__ bw,
                          const float* __restrict__ sw,
                          const float* __restrict__ ss,
                          uint4* __restrict__ wcf) {
    int idx = blockIdx.x * blockDim.x + threadIdx.x;
    if (idx >= N_LAYERS * NSTEP * 4 * 64) return;
    int lane = idx & 63;
    int nt   = (idx >> 6) & 3;
    int s    = (idx >> 8) % NSTEP;
    int l    = idx / (64 * 4 * NSTEP);
    int o = nt * 16 + (lane & 15);

    unsigned short hi[8], lo[8];
#pragma unroll
    for (int j = 0; j < 8; ++j) {
        int k = s * 32 + ((lane >> 4) << 3) + j;
        int d = k / 9;
        int r = k - d * 9;
        float v;
        if (r == 0) v = bw[(l * DIM + o) * DIM + d];
        else        v = sw[((l * DIM + o) * DIM + d) * N_COEF + (r - 1)] *
                        ss[(l * DIM + o) * DIM + d];
        _Float16 h = (_Float16)v;
        float lv = v - (float)h;
        _Float16 lo16 = (_Float16)lv;
        hi[j] = __builtin_bit_cast(unsigned short, h);
        lo[j] = __builtin_bit_cast(unsigned short, lo16);
    }
    uint4 uh, ul;
    uh.x = (unsigned)hi[0] | ((unsigned)hi[1] << 16);
    uh.y = (unsigned)hi[2] | ((unsigned)hi[3] << 16);
    uh.z = (unsigned)hi[4] | ((unsigned)hi[5] << 16);
    uh.w = (unsigned)hi[6] | ((unsigned)hi[7] << 16);
    ul.x = (unsigned)lo[0] | ((unsigned)lo[1] << 16);
    ul.y = (unsigned)lo[2] | ((unsigned)lo[3] << 16);
    ul.z = (unsigned)lo[4] | ((unsigned)lo[5] << 16);
    ul.w = (unsigned)lo[6] | ((unsigned)lo[7] << 16);
    wcf[(((l * 2 + 0) * NSTEP + s) * 4 + nt) * 64 + lane] = uh;
    wcf[(((l * 2 + 1) * NSTEP + s) * 4 + nt) * 64 + lane] = ul;
}

// ---------------------------------------------------------------------------
// row_ptr build: one binary search per node, once per call (reused 3x).
// ---------------------------------------------------------------------------
__global__ void build_rowptr(const int* __restrict__ erow, int* __restrict__ rp) {
    int i = blockIdx.x * blockDim.x + threadIdx.x;
    if (i > N_NODES) return;
    if (i == N_NODES) { rp[i] = N_EDGES; return; }
    int a = 0, b = N_EDGES;
    while (a < b) { int m = (a + b) >> 1; if (erow[m] < i) a = m + 1; else b = m; }
    rp[i] = a;
}

// ---------------------------------------------------------------------------
// SpMM, software-pipelined: ping-pong batches of 8 edges; metadata for batch
// b+1 prefetched while batch b's 8 gathers are in flight. Wave per node,
// lane = feature d.
// ---------------------------------------------------------------------------
#define META8(C, V, BASE)                                              \
    _Pragma("unroll")                                                  \
    for (int i = 0; i < 8; ++i) {                                      \
        int e = (BASE) + i;                                            \
        if (e < end) { C[i] = ecol[e]; V[i] = ev[e]; }                 \
        else         { C[i] = 0;       V[i] = 0.f; }                   \
    }

#define GATHER8(C, V)                                                  \
    _Pragma("unroll")                                                  \
    for (int i = 0; i < 8; ++i)                                        \
        acc += V[i] * x[C[i] * DIM + lane];

__global__ __launch_bounds__(256) void spmm_kernel(const int* __restrict__ rp,
                                                   const int* __restrict__ ecol,
                                                   const float* __restrict__ ev,
                                                   const float* __restrict__ x,
                                                   float* __restrict__ y) {
    int wid = (blockIdx.x * blockDim.x + threadIdx.x) >> 6;
    int lane = threadIdx.x & 63;
    if (wid >= N_NODES) return;
    int e0 = rp[wid], end = rp[wid + 1];
    int deg = end - e0;
    int nb = (deg + 7) >> 3;

    float acc = 0.f;
    int ca[8], cb[8];
    float va[8], vb[8];

    META8(ca, va, e0)
    for (int b = 0; b < nb; b += 2) {
        bool has1 = (b + 1) < nb;
        if (has1) { META8(cb, vb, e0 + (b + 1) * 8) }
        GATHER8(ca, va)
        if (b + 2 < nb) { META8(ca, va, e0 + (b + 2) * 8) }
        if (has1) { GATHER8(cb, vb) }
    }
    y[wid * DIM + lane] = acc;
}

// ---------------------------------------------------------------------------
// Spline window: 4 nonzero cubic B-spline bases as f16 pairs, positioned into
// an 8-slot (128-bit) window via 64-bit shifts. Slots kb=0..3 -> lo, 4..7 -> hi.
// ---------------------------------------------------------------------------
__device__ __forceinline__ void spline_window(float xv, unsigned long long& lo,
                                              unsigned long long& hi) {
    float t = xv * 2.5f + 5.5f;        // grid units on extended grid, h=0.4
    float fl = floorf(t);
    float u = t - fl;
    int c = (int)fl;
    bool valid = (t >= 0.f) && (t < 11.f);
    float u2 = u * u, u3 = u2 * u, um = 1.f - u;
    const float k6 = 1.f / 6.f;
    float N0 = um * um * um * k6;
    float N1 = (3.f * u3 - 6.f * u2 + 4.f) * k6;
    float N2 = (-3.f * u3 + 3.f * u2 + 3.f * u + 1.f) * k6;
    float N3 = u3 * k6;
    if (!valid) { N0 = 0.f; N1 = 0.f; N2 = 0.f; N3 = 0.f; }
    unsigned n01 = f16u(N0) | (f16u(N1) << 16);
    unsigned n23 = f16u(N2) | (f16u(N3) << 16);
    unsigned long long big = (unsigned long long)n01 | ((unsigned long long)n23 << 32);
    int qb = c - 3;
    qb = qb < -3 ? -3 : (qb > 7 ? 7 : qb);   // invalid => big==0, clamp keeps shifts legal
    int sh = qb * 16;
    lo = 0; hi = 0;
    if (sh >= 0) {
        if (sh < 64) { lo = big << sh; hi = (big >> 1) >> (63 - sh); }  // N3>=0 => bit63==0
        else         { hi = big << (sh - 64); }
    } else {
        lo = big >> (-sh);
    }
}

// ---------------------------------------------------------------------------
// Fused KANLinear via f16 MFMA (16x16x32), weights hi/lo (2 products).
// PERSISTENT: each block loads its o-tile B-fragments to registers ONCE
// (36 x f16x8 = 144 VGPR, launch_bounds(256,2) gives the 256-VGPR budget),
// then loops over node tiles. LDS: XOR-swizzled row-major [32 nodes][576 f16].
// 4 independent MFMA accumulation chains cover MFMA latency.
// ---------------------------------------------------------------------------
__global__ __launch_bounds__(256, 2) void kan_mfma(const float* __restrict__ xin,
                                                   const uint4* __restrict__ wl,
                                                   float* __restrict__ out) {
    __shared__ alignas(16) char lds[NTILE * 1152];  // 36864 B

    int tid = threadIdx.x;
    int lane = tid & 63;
    int w = tid >> 6;

    // --- load B fragments (hi/lo) for this wave's o-tile, once ---
    f16x8 bhi[NSTEP], blo[NSTEP];
#pragma unroll
    for (int s = 0; s < NSTEP; ++s) {
        bhi[s] = __builtin_bit_cast(f16x8, wl[((0 * NSTEP + s) * 4 + w) * 64 + lane]);
        blo[s] = __builtin_bit_cast(f16x8, wl[((1 * NSTEP + s) * 4 + w) * 64 + lane]);
    }

    int fn = tid >> 3;
    int fq = tid & 7;
    int Xsw = (fn & 7) << 4;
    int lbase = fn * 1152;
    int row = lane & 15, kg = lane >> 4;
    int xr = (row & 7) << 4;
    int rb0 = row * 1152;
    int rb1 = (16 + row) * 1152;
    int o = w * 16 + row;
    int rbase = kg * 4;

    for (int tile = blockIdx.x; tile < KAN_TILES; tile += gridDim.x) {
        int node0 = tile * NTILE;
        const float* xrow = &xin[(size_t)(node0 + fn) * DIM];

        // ---- feature phase ----
#pragma unroll
        for (int i = 0; i < 2; ++i) {
            float4 xv4 = *(const float4*)(xrow + fq * 4 + i * 32);
#pragma unroll
            for (int p = 0; p < 2; ++p) {
                int d = fq * 4 + i * 32 + p * 2;   // even
                float xe = p ? xv4.z : xv4.x;
                float xo = p ? xv4.w : xv4.y;

                float se_f = xe * __builtin_amdgcn_rcpf(1.f + __expf(-xe));
                float so_f = xo * __builtin_amdgcn_rcpf(1.f + __expf(-xo));
                unsigned se = f16u(se_f), so = f16u(so_f);

                unsigned long long loE, hiE, loO, hiO;
                spline_window(xe, loE, hiE);
                spline_window(xo, loO, hiO);

                unsigned wv[9];
                wv[0] = se | ((unsigned)loE << 16);
                wv[1] = (unsigned)(loE >> 16);
                wv[2] = (unsigned)(loE >> 48) | ((unsigned)hiE << 16);
                wv[3] = (unsigned)(hiE >> 16);
                wv[4] = (unsigned)(hiE >> 48) | (so << 16);
                wv[5] = (unsigned)loO;
                wv[6] = (unsigned)(loO >> 32);
                wv[7] = (unsigned)hiO;
                wv[8] = (unsigned)(hiO >> 32);

                int base = lbase + 18 * d;   // d even -> 4B aligned
#pragma unroll
                for (int j = 0; j < 9; ++j)
                    *(unsigned*)(&lds[(base + 4 * j) ^ Xsw]) = wv[j];
            }
        }
        __syncthreads();

        // ---- MFMA phase: 4 independent chains ----
        f32x4 a0h = {0.f, 0.f, 0.f, 0.f}, a0l = {0.f, 0.f, 0.f, 0.f};
        f32x4 a1h = {0.f, 0.f, 0.f, 0.f}, a1l = {0.f, 0.f, 0.f, 0.f};
#pragma unroll
        for (int s = 0; s < NSTEP; ++s) {
            int pofs = ((s * 4 + kg) << 4) ^ xr;
            f16x8 a0 = *(const f16x8*)(&lds[rb0 + pofs]);
            f16x8 a1 = *(const f16x8*)(&lds[rb1 + pofs]);
            a0h = __builtin_amdgcn_mfma_f32_16x16x32_f16(a0, bhi[s], a0h, 0, 0, 0);
            a0l = __builtin_amdgcn_mfma_f32_16x16x32_f16(a0, blo[s], a0l, 0, 0, 0);
            a1h = __builtin_amdgcn_mfma_f32_16x16x32_f16(a1, bhi[s], a1h, 0, 0, 0);
            a1l = __builtin_amdgcn_mfma_f32_16x16x32_f16(a1, blo[s], a1l, 0, 0, 0);
        }

        // ---- store: C layout col=lane&15, row=(lane>>4)*4+r ----
#pragma unroll
        for (int r = 0; r < 4; ++r) {
            out[(size_t)(node0 + rbase + r) * DIM + o]      = a0h[r] + a0l[r];
            out[(size_t)(node0 + 16 + rbase + r) * DIM + o] = a1h[r] + a1l[r];
        }
        __syncthreads();
    }
}

extern "C" void kernel_launch(void* const* d_in, const int* in_sizes, int n_in,
                              void* d_out, int out_size, void* d_ws, size_t ws_size,
                              hipStream_t stream) {
    const float* x     = (const float*)d_in[0];
    const float* eval_ = (const float*)d_in[1];
    const float* bw    = (const float*)d_in[2];
    const float* sw    = (const float*)d_in[3];
    const float* ss    = (const float*)d_in[4];
    const int*   erow  = (const int*)d_in[5];
    const int*   ecol  = (const int*)d_in[6];
    float* out = (float*)d_out;

    // ws layout: [A: 25.6MB][wcf: 884736B][row_ptr: 400004B]
    float* A   = (float*)d_ws;
    uint4* wcf = (uint4*)((char*)d_ws + (size_t)N_NODES * DIM * sizeof(float));
    int*   rp  = (int*)((char*)d_ws + (size_t)N_NODES * DIM * sizeof(float) + 884736);

    const size_t WL = (size_t)2 * NSTEP * 4 * 64;  // uint4 per layer

    build_wcf<<<(N_LAYERS * NSTEP * 4 * 64 + 255) / 256, 256, 0, stream>>>(bw, sw, ss, wcf);
    build_rowptr<<<(N_NODES + 256) / 256, 256, 0, stream>>>(erow, rp);

    const int SPMM_BLOCKS = N_NODES / 4;

    spmm_kernel<<<SPMM_BLOCKS, 256, 0, stream>>>(rp, ecol, eval_, x, out);
    kan_mfma<<<KAN_GRID, 256, 0, stream>>>(out, wcf + 0 * WL, A);
    kan_mfma<<<KAN_GRID, 256, 0, stream>>>(A,   wcf + 1 * WL, out);

    spmm_kernel<<<SPMM_BLOCKS, 256, 0, stream>>>(rp, ecol, eval_, out, A);
    kan_mfma<<<KAN_GRID, 256, 0, stream>>>(A,   wcf + 2 * WL, out);
    kan_mfma<<<KAN_GRID, 256, 0, stream>>>(out, wcf + 3 * WL, A);

    spmm_kernel<<<SPMM_BLOCKS, 256, 0, stream>>>(rp, ecol, eval_, A, out);
    kan_mfma<<<KAN_GRID, 256, 0, stream>>>(out, wcf + 4 * WL, A);
    kan_mfma<<<KAN_GRID, 256, 0, stream>>>(A,   wcf + 5 * WL, out);
}